// Round 4
// baseline (2584.469 us; speedup 1.0000x reference)
//
#include <hip/hip_runtime.h>
#include <math.h>

#define NN 8192
#define NH 1024

typedef __bf16 bf16x8 __attribute__((ext_vector_type(8)));
typedef float floatx4 __attribute__((ext_vector_type(4)));
typedef unsigned short us8 __attribute__((ext_vector_type(8)));
typedef unsigned short us;

__device__ __forceinline__ unsigned short f2bf(float f) {
  unsigned int u = __float_as_uint(f);
  u += 0x7fffu + ((u >> 16) & 1u);
  return (unsigned short)(u >> 16);
}

__device__ __forceinline__ void async16(const void* g, void* l) {
  __builtin_amdgcn_global_load_lds(
      (__attribute__((address_space(1))) void*)(g),
      (__attribute__((address_space(3))) void*)(l), 16, 0, 0);
}

// ===== 3-stage pipelined GEMM: C = A(8192 x K) * Bt(128N x K)^T ==============
// grid 512 (64 M x 8 N tiles), XCD-swizzled, 256 thr. 3 rotating LDS stages;
// manual s_waitcnt vmcnt(4) + s_barrier keeps 2 stages (8 loads/thread) in
// flight -- never drains to vmcnt(0) inside the K-loop (AITER-style).
// EPI 0: s = 0.3*acc + 0.7*aux(h0);            write iof(supf), outb(supb)
// EPI 1: o = relu(th*acc + (1-th)*aux + iof);  write iof(hf), fused-T -> hTb
// EPI 2: o = elu(...);                         write iof(hf), outb(hb)
template<int EPI>
__global__ __launch_bounds__(256)
void gemm_db(const us* __restrict__ A, const us* __restrict__ Bt, int K,
             const float* __restrict__ aux, float* __restrict__ iof,
             us* __restrict__ outb, us* __restrict__ hTb, float theta)
{
  __shared__ __align__(16) us lsm[24576];  // 3 x (4K A + 4K B) us = 48 KB
  const int id = blockIdx.x;
  const int xcd = id & 7, slot = id >> 3;
  const int xt = slot & 7;
  const int yt = xcd + 8 * (slot >> 3);

  const int tid  = threadIdx.x;
  const int lane = tid & 63;
  const int wave = tid >> 6;
  const long tileM = (long)yt * 128;
  const long tileN = (long)xt * 128;
  const int wm = (wave & 1) * 64;
  const int wn = (wave >> 1) * 64;

  const us* gA0 = A + (tileM + (tid >> 2)) * (long)K + (tid & 3) * 8;
  const us* gA1 = gA0 + 64L * K;
  const us* gB0 = Bt + (tileN + (tid >> 2)) * (long)K + (tid & 3) * 8;
  const us* gB1 = gB0 + 64L * K;
  us* lA = lsm;               // 3 stages x 4096 us
  us* lB = lsm + 12288;       // 3 stages x 4096 us
  const int lo = tid * 8;

  const int fr = lane & 15;
  const int q8 = (lane >> 4) * 8;

  floatx4 zero4 = {0.f, 0.f, 0.f, 0.f};
  floatx4 acc[4][4];
#pragma unroll
  for (int i = 0; i < 4; ++i)
#pragma unroll
    for (int j = 0; j < 4; ++j) acc[i][j] = zero4;

  // prologue: stages 0 and 1
  async16(gA0, lA + lo);
  async16(gA1, lA + lo + 2048);
  async16(gB0, lB + lo);
  async16(gB1, lB + lo + 2048);
  async16(gA0 + 32, lA + 4096 + lo);
  async16(gA1 + 32, lA + 4096 + lo + 2048);
  async16(gB0 + 32, lB + 4096 + lo);
  async16(gB1 + 32, lB + 4096 + lo + 2048);

  const int nkt = K >> 5;
  int cs = 0, is = 2;
  for (int kt = 0; kt < nkt; ++kt) {
    // oldest stage (kt) complete; keep next stage's 4 loads in flight
    asm volatile("s_waitcnt vmcnt(4)\n\ts_barrier" ::: "memory");
    int kf = kt + 2;
    if (kf >= nkt) kf = nkt - 1;          // clamped prefetch keeps invariant
    const int k0 = kf << 5;
    const int ofs = is << 12;
    async16(gA0 + k0, lA + ofs + lo);
    async16(gA1 + k0, lA + ofs + lo + 2048);
    async16(gB0 + k0, lB + ofs + lo);
    async16(gB1 + k0, lB + ofs + lo + 2048);

    const int b = cs << 12;
    bf16x8 af[4], bfr[4];
#pragma unroll
    for (int i = 0; i < 4; ++i)
      af[i] = *(const bf16x8*)&lA[b + (wm + 16 * i + fr) * 32 + q8];
#pragma unroll
    for (int j = 0; j < 4; ++j)
      bfr[j] = *(const bf16x8*)&lB[b + (wn + 16 * j + fr) * 32 + q8];
#pragma unroll
    for (int i = 0; i < 4; ++i)
#pragma unroll
      for (int j = 0; j < 4; ++j)
        acc[i][j] = __builtin_amdgcn_mfma_f32_16x16x32_bf16(af[i], bfr[j], acc[i][j], 0, 0, 0);
    cs = (cs == 2) ? 0 : cs + 1;
    is = (is == 2) ? 0 : is + 1;
  }

  __syncthreads();  // drain outstanding prefetches before LDS reuse / exit
  us* ldsT = lsm;   // [col][row], stride 136 (EPI 1 only)
  const int crow = (lane >> 4) * 4;
#pragma unroll
  for (int i = 0; i < 4; ++i) {
#pragma unroll
    for (int j = 0; j < 4; ++j) {
#pragma unroll
      for (int r = 0; r < 4; ++r) {
        int lr = wm + 16 * i + crow + r;
        int lc = wn + 16 * j + fr;
        long idx = (tileM + lr) * NH + tileN + lc;
        float v = acc[i][j][r];
        if (EPI == 0) {
          float s = 0.3f * v + 0.7f * aux[idx];
          iof[idx] = s;
          outb[idx] = f2bf(s);
        } else {
          float o = theta * v + (1.f - theta) * aux[idx] + iof[idx];
          o = (EPI == 1) ? fmaxf(o, 0.f) : (o > 0.f ? o : __expf(o) - 1.f);
          iof[idx] = o;
          if (EPI == 1) ldsT[lc * 136 + lr] = f2bf(o);
          if (EPI == 2) outb[idx] = f2bf(o);
        }
      }
    }
  }
  if (EPI == 1) {
    __syncthreads();
    int c = tid >> 1, half = tid & 1;
#pragma unroll
    for (int it = 0; it < 8; ++it) {
      int r = half * 64 + it * 8;
      us8 v = *(const us8*)&ldsT[c * 136 + r];
      *(us8*)&hTb[(tileN + c) * 8192L + tileM + r] = v;
    }
  }
}

// ======== classifier head as MFMA GEMM: out = sigmoid(relu(h@W1+b1)@W3+b3) ===
__global__ __launch_bounds__(256)
void cls_gemm(const us* __restrict__ hb, const us* __restrict__ W1t,
              const float* __restrict__ b1, const float* __restrict__ W3,
              const float* __restrict__ b3, float* __restrict__ out)
{
  __shared__ __align__(16) us lA[4096];
  __shared__ __align__(16) us lB[2048];
  const int tid = threadIdx.x, lane = tid & 63, wave = tid >> 6;
  const long tileM = (long)blockIdx.x * 128;
  const us* gA0 = hb + (tileM + (tid >> 2)) * 1024L + (tid & 3) * 8;
  const us* gA1 = gA0 + 64 * 1024L;
  const us* gB0 = W1t + (tid >> 2) * 1024L + (tid & 3) * 8;
  const int fr = lane & 15, q8 = (lane >> 4) * 8;
  const int wm = wave * 32;

  floatx4 zero4 = {0.f, 0.f, 0.f, 0.f};
  floatx4 acc[2][4];
#pragma unroll
  for (int i = 0; i < 2; ++i)
#pragma unroll
    for (int j = 0; j < 4; ++j) acc[i][j] = zero4;

  for (int kt = 0; kt < 32; ++kt) {
    const int k0 = kt << 5;
    async16(gA0 + k0, lA + tid * 8);
    async16(gA1 + k0, lA + 2048 + tid * 8);
    async16(gB0 + k0, lB + tid * 8);
    __syncthreads();
    bf16x8 af[2], bfr[4];
#pragma unroll
    for (int i = 0; i < 2; ++i)
      af[i] = *(const bf16x8*)&lA[(wm + 16 * i + fr) * 32 + q8];
#pragma unroll
    for (int j = 0; j < 4; ++j)
      bfr[j] = *(const bf16x8*)&lB[(16 * j + fr) * 32 + q8];
#pragma unroll
    for (int i = 0; i < 2; ++i)
#pragma unroll
      for (int j = 0; j < 4; ++j)
        acc[i][j] = __builtin_amdgcn_mfma_f32_16x16x32_bf16(af[i], bfr[j], acc[i][j], 0, 0, 0);
    __syncthreads();
  }

  float b1v[4], w3v[4];
#pragma unroll
  for (int j = 0; j < 4; ++j) { b1v[j] = b1[16 * j + fr]; w3v[j] = W3[16 * j + fr]; }
  const float b3v = b3[0];
  const int crow = (lane >> 4) * 4;
#pragma unroll
  for (int i = 0; i < 2; ++i)
#pragma unroll
    for (int r = 0; r < 4; ++r) {
      float v = 0.f;
#pragma unroll
      for (int j = 0; j < 4; ++j)
        v += fmaxf(acc[i][j][r] + b1v[j], 0.f) * w3v[j];
      v += __shfl_xor(v, 1);
      v += __shfl_xor(v, 2);
      v += __shfl_xor(v, 4);
      v += __shfl_xor(v, 8);
      if (fr == 0)
        out[tileM + wm + 16 * i + crow + r] = 1.f / (1.f + __expf(-(v + b3v)));
    }
}

// ---------------- fp32 (R x C) -> bf16 transposed (C x R) ----------------
__global__ __launch_bounds__(256)
void transpose_f32_bf16(const float* __restrict__ src, us* __restrict__ dst,
                        int R, int C) {
  __shared__ float t[32][33];
  int tid = threadIdx.x;
  int tx = tid & 31, ty = tid >> 5;
  long r0 = (long)blockIdx.y * 32, c0 = (long)blockIdx.x * 32;
#pragma unroll
  for (int i = 0; i < 32; i += 8)
    t[ty + i][tx] = src[(r0 + ty + i) * C + c0 + tx];
  __syncthreads();
#pragma unroll
  for (int i = 0; i < 32; i += 8)
    dst[(c0 + ty + i) * R + r0 + tx] = f2bf(t[tx][ty + i]);
}

// ---------------- fp32 -> bf16 elementwise (dist) ----------------
__global__ __launch_bounds__(256)
void f32_to_bf16_vec(const float* __restrict__ s, us* __restrict__ d) {
  long i = (blockIdx.x * 256L + threadIdx.x) * 4;
  float4 v = *(const float4*)(s + i);
  *(ushort4*)(d + i) = make_ushort4(f2bf(v.x), f2bf(v.y), f2bf(v.z), f2bf(v.w));
}

// ---------------- h0 = relu(x @ fc_W + fc_b) ----------------
__global__ __launch_bounds__(256)
void fc_kernel(const float* __restrict__ x, const float* __restrict__ W,
               const float* __restrict__ b, float* __restrict__ h0f,
               float* __restrict__ hf) {
  __shared__ float xs[64];
  int row = blockIdx.x, tid = threadIdx.x;
  if (tid < 63) xs[tid] = x[row * 63 + tid];
  __syncthreads();
#pragma unroll
  for (int q = 0; q < 4; ++q) {
    int c = tid + q * 256;
    float s = b[c];
    for (int k = 0; k < 63; ++k) s += xs[k] * W[k * NH + c];
    s = fmaxf(s, 0.f);
    long idx = (long)row * NH + c;
    h0f[idx] = s;
    hf[idx] = s;
  }
}

// ---------------- va1 = gat_W @ a1, va2 = gat_W @ a2 ----------------
__global__ __launch_bounds__(256)
void wv_kernel(const float* __restrict__ W, const float* __restrict__ a,
               float* __restrict__ va1, float* __restrict__ va2) {
  int k = blockIdx.x, tid = threadIdx.x;
  float s1 = 0.f, s2 = 0.f;
  for (int n = tid; n < NH; n += 256) {
    float w = W[(long)k * NH + n];
    s1 += w * a[n];
    s2 += w * a[NH + n];
  }
#pragma unroll
  for (int o = 32; o; o >>= 1) { s1 += __shfl_down(s1, o); s2 += __shfl_down(s2, o); }
  __shared__ float r1[4], r2[4];
  int wave = tid >> 6;
  if ((tid & 63) == 0) { r1[wave] = s1; r2[wave] = s2; }
  __syncthreads();
  if (tid == 0) {
    va1[k] = r1[0] + r1[1] + r1[2] + r1[3];
    va2[k] = r2[0] + r2[1] + r2[2] + r2[3];
  }
}

// ---------------- f = h @ va1, g = h @ va2 ----------------
__global__ __launch_bounds__(256)
void fg_kernel(const float* __restrict__ h, const float* __restrict__ va1,
               const float* __restrict__ va2, float* __restrict__ fv,
               float* __restrict__ gv) {
  int row = blockIdx.x, tid = threadIdx.x;
  float s1 = 0.f, s2 = 0.f;
  for (int k = tid; k < NH; k += 256) {
    float v = h[(long)row * NH + k];
    s1 += v * va1[k];
    s2 += v * va2[k];
  }
#pragma unroll
  for (int o = 32; o; o >>= 1) { s1 += __shfl_down(s1, o); s2 += __shfl_down(s2, o); }
  __shared__ float r1[4], r2[4];
  int wave = tid >> 6;
  if ((tid & 63) == 0) { r1[wave] = s1; r2[wave] = s2; }
  __syncthreads();
  if (tid == 0) {
    fv[row] = r1[0] + r1[1] + r1[2] + r1[3];
    gv[row] = r2[0] + r2[1] + r2[2] + r2[3];
  }
}

// ---------------- attention pass 1: per-row max & denom ----------------
__global__ __launch_bounds__(256)
void attn_ml(const int* __restrict__ adj, const float* __restrict__ f,
             const float* __restrict__ g, float* __restrict__ Mr,
             float* __restrict__ Lr) {
  const int row = blockIdx.x, tid = threadIdx.x;
  const float fi = f[row];
  const int4* arow = (const int4*)(adj + (long)row * NN);
  float m = -3.0e38f, s = 0.f;
  for (int c = tid; c < NN / 4; c += 256) {
    int4 a = arow[c];
    float4 gg = *(const float4*)(g + c * 4);
#pragma unroll
    for (int t = 0; t < 4; ++t) {
      int av = (t == 0) ? a.x : (t == 1) ? a.y : (t == 2) ? a.z : a.w;
      float gvv = (t == 0) ? gg.x : (t == 1) ? gg.y : (t == 2) ? gg.z : gg.w;
      if (av > 0) {
        float e = fi + gvv;
        e = e > 0.f ? e : 0.2f * e;
        if (e > m) { s = s * __expf(m - e) + 1.f; m = e; }
        else s += __expf(e - m);
      }
    }
  }
#pragma unroll
  for (int o = 32; o; o >>= 1) {
    float m2 = __shfl_down(m, o), s2 = __shfl_down(s, o);
    float mn = fmaxf(m, m2);
    s = s * __expf(m - mn) + s2 * __expf(m2 - mn);
    m = mn;
  }
  __shared__ float ms[4], ss[4];
  int wave = tid >> 6;
  if ((tid & 63) == 0) { ms[wave] = m; ss[wave] = s; }
  __syncthreads();
  if (tid == 0) {
    float mm = ms[0], sv = ss[0];
    for (int w = 1; w < 4; ++w) {
      float mn = fmaxf(mm, ms[w]);
      sv = sv * __expf(mm - mn) + ss[w] * __expf(ms[w] - mn);
      mm = mn;
    }
    Mr[row] = mm;
    Lr[row] = sv;
  }
}

// ---------------- attention pass 2: P (bf16) ----------------
__global__ __launch_bounds__(256)
void attn_p(const int* __restrict__ adj, const float* __restrict__ f,
            const float* __restrict__ g, const float* __restrict__ Mr,
            const float* __restrict__ Lr, us* __restrict__ P) {
  long gid = blockIdx.x * 256L + threadIdx.x;
  int row = (int)(gid >> 11);
  int jc = (int)(gid & 2047) * 4;
  float fi = f[row], m = Mr[row], l = Lr[row];
  bool uni = !(l > 0.f);
  float inv = uni ? 0.f : 1.f / l;
  int4 a = *(const int4*)(adj + ((long)row << 13) + jc);
  float4 gg = *(const float4*)(g + jc);
  float p[4];
#pragma unroll
  for (int t = 0; t < 4; ++t) {
    int av = (t == 0) ? a.x : (t == 1) ? a.y : (t == 2) ? a.z : a.w;
    float gvv = (t == 0) ? gg.x : (t == 1) ? gg.y : (t == 2) ? gg.z : gg.w;
    float e = fi + gvv;
    e = e > 0.f ? e : 0.2f * e;
    float pv = (av > 0) ? __expf(e - m) * inv : 0.f;
    if (uni) pv = 1.f / (float)NN;
    p[t] = pv;
  }
  *(ushort4*)(P + ((long)row << 13) + jc) =
      make_ushort4(f2bf(p[0]), f2bf(p[1]), f2bf(p[2]), f2bf(p[3]));
}

extern "C" void kernel_launch(void* const* d_in, const int* in_sizes, int n_in,
                              void* d_out, int out_size, void* d_ws, size_t ws_size,
                              hipStream_t stream) {
  const float* x      = (const float*)d_in[0];
  const float* dist   = (const float*)d_in[1];
  const int*   adj    = (const int*)d_in[2];
  const float* fc_W   = (const float*)d_in[3];
  const float* fc_b   = (const float*)d_in[4];
  const float* conv_W = (const float*)d_in[5];
  const float* gat_W  = (const float*)d_in[6];
  const float* gat_a  = (const float*)d_in[7];
  const float* cls1_W = (const float*)d_in[8];
  const float* cls1_b = (const float*)d_in[9];
  const float* cls3_W = (const float*)d_in[10];
  const float* cls3_b = (const float*)d_in[11];
  float* out = (float*)d_out;

  char* p = (char*)d_ws;
  auto alloc = [&](size_t bytes) {
    char* r = p;
    p += (bytes + 255) & ~(size_t)255;
    return r;
  };
  us* distb   = (us*)alloc((size_t)NN * NN * 2);
  float* h0f  = (float*)alloc((size_t)NN * NH * 4);
  float* hf   = (float*)alloc((size_t)NN * NH * 4);
  float* supf = (float*)alloc((size_t)NN * NH * 4);
  us* supb    = (us*)alloc((size_t)NN * NH * 2);
  us* hb      = (us*)alloc((size_t)NN * NH * 2);
  us* hTb     = (us*)alloc((size_t)NN * NH * 2);
  us* convWT  = (us*)alloc((size_t)7 * NH * NH * 2);
  us* gatWT   = (us*)alloc((size_t)NH * NH * 2);
  us* W1t     = (us*)alloc((size_t)64 * NH * 2);
  float* va1 = (float*)alloc(NH * 4);
  float* va2 = (float*)alloc(NH * 4);
  float* fv  = (float*)alloc(NN * 4);
  float* gv  = (float*)alloc(NN * 4);
  float* Mr  = (float*)alloc(NN * 4);
  float* Lr  = (float*)alloc(NN * 4);

  float th[7];
  for (int l = 0; l < 7; ++l) {
    float t = logf(1.5f / (float)(l + 1) + 1.f);
    th[l] = t < 1.f ? t : 1.f;
  }
  float th9 = logf(1.5f / 9.f + 1.f);

  f32_to_bf16_vec<<<(NN * (long)NN) / (4 * 256), 256, 0, stream>>>(dist, distb);
  for (int i = 0; i < 7; ++i)
    transpose_f32_bf16<<<dim3(32, 32), 256, 0, stream>>>(
        conv_W + (size_t)i * NH * NH, convWT + (size_t)i * NH * NH, NH, NH);
  transpose_f32_bf16<<<dim3(32, 32), 256, 0, stream>>>(gat_W, gatWT, NH, NH);
  transpose_f32_bf16<<<dim3(2, 32), 256, 0, stream>>>(cls1_W, W1t, NH, 64);

  fc_kernel<<<NN, 256, 0, stream>>>(x, fc_W, fc_b, h0f, hf);
  transpose_f32_bf16<<<dim3(NH / 32, NN / 32), 256, 0, stream>>>(hf, hTb, NN, NH);

  for (int l = 0; l < 7; ++l) {
    gemm_db<0><<<512, 256, 0, stream>>>(distb, hTb, NN, h0f, supf, supb, nullptr, 0.f);
    gemm_db<1><<<512, 256, 0, stream>>>(supb, convWT + (size_t)l * NH * NH, NH,
                                        supf, hf, nullptr, hTb, th[l]);
  }

  wv_kernel<<<NH, 256, 0, stream>>>(gat_W, gat_a, va1, va2);
  fg_kernel<<<NN, 256, 0, stream>>>(hf, va1, va2, fv, gv);
  attn_ml<<<NN, 256, 0, stream>>>(adj, fv, gv, Mr, Lr);
  attn_p<<<(NN * (long)NN) / (4 * 256), 256, 0, stream>>>(adj, fv, gv, Mr, Lr, distb);

  gemm_db<0><<<512, 256, 0, stream>>>(distb, hTb, NN, h0f, supf, supb, nullptr, 0.f);
  gemm_db<2><<<512, 256, 0, stream>>>(supb, gatWT, NH, supf, hf, hb, nullptr, th9);

  cls_gemm<<<64, 256, 0, stream>>>(hb, W1t, cls1_b, cls3_W, cls3_b, out);
}

// Round 5
// 2425.357 us; speedup vs baseline: 1.0656x; 1.0656x over previous
//
#include <hip/hip_runtime.h>
#include <math.h>

#define NN 8192
#define NH 1024

typedef __bf16 bf16x8 __attribute__((ext_vector_type(8)));
typedef float floatx4 __attribute__((ext_vector_type(4)));
typedef unsigned short us8 __attribute__((ext_vector_type(8)));
typedef unsigned short us;

__device__ __forceinline__ unsigned short f2bf(float f) {
  unsigned int u = __float_as_uint(f);
  u += 0x7fffu + ((u >> 16) & 1u);
  return (unsigned short)(u >> 16);
}

__device__ __forceinline__ void async16(const void* g, void* l) {
  __builtin_amdgcn_global_load_lds(
      (__attribute__((address_space(1))) void*)(g),
      (__attribute__((address_space(3))) void*)(l), 16, 0, 0);
}

// ===== big GEMM (K=8192, EPI0): sup = 0.3*(A@Bt^T) + 0.7*h0 =================
// 256x128 block tile, wave tile 128x64, grid 256 (1 block/CU), 96 KB LDS,
// 4 static stages, K-loop unrolled x4 (all LDS offsets are immediates),
// s_waitcnt vmcnt(12)+s_barrier keeps 2 stages in flight (never drains).
// LDS traffic: 72 KB per 2.1 MFLOP per iter -- 2.67x less than 128x128.
__global__ __launch_bounds__(256)
void gemm_big(const us* __restrict__ A, const us* __restrict__ Bt,
              const float* __restrict__ aux, float* __restrict__ supf,
              us* __restrict__ supb)
{
  // lB first (4 x 4096 us), then lA (4 x 8192 us) -> A imms fit base+imm
  __shared__ __align__(16) us lsm[49152];  // 96 KB
  us* lB = lsm;            // stage s at s*4096
  us* lA = lsm + 16384;    // stage s at s*8192

  const int id = blockIdx.x;
  const int yt = id & 31;   // M-tile: ids of one stripe differ by 32 -> same XCD
  const int xt = id >> 5;

  const int tid  = threadIdx.x;
  const int lane = tid & 63;
  const int wave = tid >> 6;
  const long tileM = (long)yt * 256;
  const long tileN = (long)xt * 128;
  const int wm = (wave & 1) * 128;
  const int wn = (wave >> 1) * 64;

  const us* gAp = A + (tileM + (tid >> 2)) * 8192L + (tid & 3) * 8;
  const us* gBp = Bt + (tileN + (tid >> 2)) * 8192L + (tid & 3) * 8;
  const int lo = tid * 8;

  const int fr = lane & 15;
  const int q8 = (lane >> 4) * 8;

  floatx4 zero4 = {0.f, 0.f, 0.f, 0.f};
  floatx4 acc[8][4];
#pragma unroll
  for (int i = 0; i < 8; ++i)
#pragma unroll
    for (int j = 0; j < 4; ++j) acc[i][j] = zero4;

#define STAGE_BIG(s, kf)                                                  \
  {                                                                       \
    const long ko = (long)(kf) << 5;                                      \
    async16(gAp + ko, lA + (s)*8192 + lo);                                \
    async16(gAp + 64 * 8192L + ko, lA + (s)*8192 + 2048 + lo);            \
    async16(gAp + 128 * 8192L + ko, lA + (s)*8192 + 4096 + lo);           \
    async16(gAp + 192 * 8192L + ko, lA + (s)*8192 + 6144 + lo);           \
    async16(gBp + ko, lB + (s)*4096 + lo);                                \
    async16(gBp + 64 * 8192L + ko, lB + (s)*4096 + 2048 + lo);            \
  }

#define COMP_BIG(s)                                                       \
  {                                                                       \
    bf16x8 af[8], bfr[4];                                                 \
    _Pragma("unroll") for (int i = 0; i < 8; ++i)                         \
        af[i] = *(const bf16x8*)&lA[(s)*8192 + (wm + 16 * i + fr) * 32 + q8]; \
    _Pragma("unroll") for (int j = 0; j < 4; ++j)                         \
        bfr[j] = *(const bf16x8*)&lB[(s)*4096 + (wn + 16 * j + fr) * 32 + q8]; \
    _Pragma("unroll") for (int i = 0; i < 8; ++i)                         \
        _Pragma("unroll") for (int j = 0; j < 4; ++j)                     \
            acc[i][j] = __builtin_amdgcn_mfma_f32_16x16x32_bf16(          \
                af[i], bfr[j], acc[i][j], 0, 0, 0);                       \
  }

#define WAITB asm volatile("s_waitcnt vmcnt(12)\n\ts_barrier" ::: "memory")

  // prologue: tiles 0,1,2 -> stages 0,1,2 (18 loads in flight)
  STAGE_BIG(0, 0)
  STAGE_BIG(1, 1)
  STAGE_BIG(2, 2)

  for (int kt = 0; kt < 256; kt += 4) {
    int k3 = kt + 3; if (k3 > 255) k3 = 255;
    int k4 = kt + 4; if (k4 > 255) k4 = 255;
    int k5 = kt + 5; if (k5 > 255) k5 = 255;
    int k6 = kt + 6; if (k6 > 255) k6 = 255;
    WAITB; STAGE_BIG(3, k3) COMP_BIG(0)
    WAITB; STAGE_BIG(0, k4) COMP_BIG(1)
    WAITB; STAGE_BIG(1, k5) COMP_BIG(2)
    WAITB; STAGE_BIG(2, k6) COMP_BIG(3)
  }
  asm volatile("s_waitcnt vmcnt(0)" ::: "memory");

  const int crow = (lane >> 4) * 4;
#pragma unroll
  for (int i = 0; i < 8; ++i)
#pragma unroll
    for (int j = 0; j < 4; ++j)
#pragma unroll
      for (int r = 0; r < 4; ++r) {
        long row = tileM + wm + 16 * i + crow + r;
        long col = tileN + wn + 16 * j + fr;
        long idx = row * NH + col;
        float s = 0.3f * acc[i][j][r] + 0.7f * aux[idx];
        supf[idx] = s;
        supb[idx] = f2bf(s);
      }
#undef STAGE_BIG
#undef COMP_BIG
#undef WAITB
}

// ===== small GEMM (K=1024) + epilogue, R3-style 2-stage static dbuf =========
// EPI 1: o = relu(th*acc + (1-th)*aux + iof); write iof(hf), fused-T -> hTb
// EPI 2: o = elu(...);                        write iof(hf), outb(hb)
template<int EPI>
__global__ __launch_bounds__(256)
void gemm_db(const us* __restrict__ A, const us* __restrict__ Bt, int K,
             const float* __restrict__ aux, float* __restrict__ iof,
             us* __restrict__ outb, us* __restrict__ hTb, float theta)
{
  __shared__ __align__(16) us lsm[EPI == 1 ? 17408 : 16384];
  const int id = blockIdx.x;
  const int xcd = id & 7, slot = id >> 3;
  const int xt = slot & 7;
  const int yt = xcd + 8 * (slot >> 3);

  const int tid  = threadIdx.x;
  const int lane = tid & 63;
  const int wave = tid >> 6;
  const long tileM = (long)yt * 128;
  const long tileN = (long)xt * 128;
  const int wm = (wave & 1) * 64;
  const int wn = (wave >> 1) * 64;

  const us* gA0 = A + (tileM + (tid >> 2)) * (long)K + (tid & 3) * 8;
  const us* gA1 = gA0 + 64L * K;
  const us* gB0 = Bt + (tileN + (tid >> 2)) * (long)K + (tid & 3) * 8;
  const us* gB1 = gB0 + 64L * K;
  us* lA = lsm;
  us* lB = lsm + 8192;
  const int lo = tid * 8;

  const int fr = lane & 15;
  const int q8 = (lane >> 4) * 8;

  floatx4 zero4 = {0.f, 0.f, 0.f, 0.f};
  floatx4 acc[4][4];
#pragma unroll
  for (int i = 0; i < 4; ++i)
#pragma unroll
    for (int j = 0; j < 4; ++j) acc[i][j] = zero4;

  async16(gA0, lA + lo);
  async16(gA1, lA + lo + 2048);
  async16(gB0, lB + lo);
  async16(gB1, lB + lo + 2048);

  const int nkt = K >> 5;
  for (int kt = 0; kt < nkt; ++kt) {
    const int b = (kt & 1) << 12;
    __syncthreads();
    if (kt + 1 < nkt) {
      const int k0 = (kt + 1) << 5;
      const int b2 = b ^ 4096;
      async16(gA0 + k0, lA + b2 + lo);
      async16(gA1 + k0, lA + b2 + lo + 2048);
      async16(gB0 + k0, lB + b2 + lo);
      async16(gB1 + k0, lB + b2 + lo + 2048);
    }
    bf16x8 af[4], bfr[4];
#pragma unroll
    for (int i = 0; i < 4; ++i)
      af[i] = *(const bf16x8*)&lA[b + (wm + 16 * i + fr) * 32 + q8];
#pragma unroll
    for (int j = 0; j < 4; ++j)
      bfr[j] = *(const bf16x8*)&lB[b + (wn + 16 * j + fr) * 32 + q8];
#pragma unroll
    for (int i = 0; i < 4; ++i)
#pragma unroll
      for (int j = 0; j < 4; ++j)
        acc[i][j] = __builtin_amdgcn_mfma_f32_16x16x32_bf16(af[i], bfr[j], acc[i][j], 0, 0, 0);
  }

  __syncthreads();
  us* ldsT = lsm;  // [col][row], stride 136 (EPI 1 only)
  const int crow = (lane >> 4) * 4;
#pragma unroll
  for (int i = 0; i < 4; ++i) {
#pragma unroll
    for (int j = 0; j < 4; ++j) {
#pragma unroll
      for (int r = 0; r < 4; ++r) {
        int lr = wm + 16 * i + crow + r;
        int lc = wn + 16 * j + fr;
        long idx = (tileM + lr) * NH + tileN + lc;
        float o = theta * acc[i][j][r] + (1.f - theta) * aux[idx] + iof[idx];
        o = (EPI == 1) ? fmaxf(o, 0.f) : (o > 0.f ? o : __expf(o) - 1.f);
        iof[idx] = o;
        if (EPI == 1) ldsT[lc * 136 + lr] = f2bf(o);
        if (EPI == 2) outb[idx] = f2bf(o);
      }
    }
  }
  if (EPI == 1) {
    __syncthreads();
    int c = tid >> 1, half = tid & 1;
#pragma unroll
    for (int it = 0; it < 8; ++it) {
      int r = half * 64 + it * 8;
      us8 v = *(const us8*)&ldsT[c * 136 + r];
      *(us8*)&hTb[(tileN + c) * 8192L + tileM + r] = v;
    }
  }
}

// ======== classifier head as MFMA GEMM: out = sigmoid(relu(h@W1+b1)@W3+b3) ===
__global__ __launch_bounds__(256)
void cls_gemm(const us* __restrict__ hb, const us* __restrict__ W1t,
              const float* __restrict__ b1, const float* __restrict__ W3,
              const float* __restrict__ b3, float* __restrict__ out)
{
  __shared__ __align__(16) us lA[4096];
  __shared__ __align__(16) us lB[2048];
  const int tid = threadIdx.x, lane = tid & 63, wave = tid >> 6;
  const long tileM = (long)blockIdx.x * 128;
  const us* gA0 = hb + (tileM + (tid >> 2)) * 1024L + (tid & 3) * 8;
  const us* gA1 = gA0 + 64 * 1024L;
  const us* gB0 = W1t + (tid >> 2) * 1024L + (tid & 3) * 8;
  const int fr = lane & 15, q8 = (lane >> 4) * 8;
  const int wm = wave * 32;

  floatx4 zero4 = {0.f, 0.f, 0.f, 0.f};
  floatx4 acc[2][4];
#pragma unroll
  for (int i = 0; i < 2; ++i)
#pragma unroll
    for (int j = 0; j < 4; ++j) acc[i][j] = zero4;

  for (int kt = 0; kt < 32; ++kt) {
    const int k0 = kt << 5;
    async16(gA0 + k0, lA + tid * 8);
    async16(gA1 + k0, lA + 2048 + tid * 8);
    async16(gB0 + k0, lB + tid * 8);
    __syncthreads();
    bf16x8 af[2], bfr[4];
#pragma unroll
    for (int i = 0; i < 2; ++i)
      af[i] = *(const bf16x8*)&lA[(wm + 16 * i + fr) * 32 + q8];
#pragma unroll
    for (int j = 0; j < 4; ++j)
      bfr[j] = *(const bf16x8*)&lB[(16 * j + fr) * 32 + q8];
#pragma unroll
    for (int i = 0; i < 2; ++i)
#pragma unroll
      for (int j = 0; j < 4; ++j)
        acc[i][j] = __builtin_amdgcn_mfma_f32_16x16x32_bf16(af[i], bfr[j], acc[i][j], 0, 0, 0);
    __syncthreads();
  }

  float b1v[4], w3v[4];
#pragma unroll
  for (int j = 0; j < 4; ++j) { b1v[j] = b1[16 * j + fr]; w3v[j] = W3[16 * j + fr]; }
  const float b3v = b3[0];
  const int crow = (lane >> 4) * 4;
#pragma unroll
  for (int i = 0; i < 2; ++i)
#pragma unroll
    for (int r = 0; r < 4; ++r) {
      float v = 0.f;
#pragma unroll
      for (int j = 0; j < 4; ++j)
        v += fmaxf(acc[i][j][r] + b1v[j], 0.f) * w3v[j];
      v += __shfl_xor(v, 1);
      v += __shfl_xor(v, 2);
      v += __shfl_xor(v, 4);
      v += __shfl_xor(v, 8);
      if (fr == 0)
        out[tileM + wm + 16 * i + crow + r] = 1.f / (1.f + __expf(-(v + b3v)));
    }
}

// ---------------- fp32 (R x C) -> bf16 transposed (C x R) ----------------
__global__ __launch_bounds__(256)
void transpose_f32_bf16(const float* __restrict__ src, us* __restrict__ dst,
                        int R, int C) {
  __shared__ float t[32][33];
  int tid = threadIdx.x;
  int tx = tid & 31, ty = tid >> 5;
  long r0 = (long)blockIdx.y * 32, c0 = (long)blockIdx.x * 32;
#pragma unroll
  for (int i = 0; i < 32; i += 8)
    t[ty + i][tx] = src[(r0 + ty + i) * C + c0 + tx];
  __syncthreads();
#pragma unroll
  for (int i = 0; i < 32; i += 8)
    dst[(c0 + ty + i) * R + r0 + tx] = f2bf(t[tx][ty + i]);
}

// ---------------- fp32 -> bf16 elementwise (dist) ----------------
__global__ __launch_bounds__(256)
void f32_to_bf16_vec(const float* __restrict__ s, us* __restrict__ d) {
  long i = (blockIdx.x * 256L + threadIdx.x) * 4;
  float4 v = *(const float4*)(s + i);
  *(ushort4*)(d + i) = make_ushort4(f2bf(v.x), f2bf(v.y), f2bf(v.z), f2bf(v.w));
}

// ---------------- h0 = relu(x @ fc_W + fc_b) ----------------
__global__ __launch_bounds__(256)
void fc_kernel(const float* __restrict__ x, const float* __restrict__ W,
               const float* __restrict__ b, float* __restrict__ h0f,
               float* __restrict__ hf) {
  __shared__ float xs[64];
  int row = blockIdx.x, tid = threadIdx.x;
  if (tid < 63) xs[tid] = x[row * 63 + tid];
  __syncthreads();
#pragma unroll
  for (int q = 0; q < 4; ++q) {
    int c = tid + q * 256;
    float s = b[c];
    for (int k = 0; k < 63; ++k) s += xs[k] * W[k * NH + c];
    s = fmaxf(s, 0.f);
    long idx = (long)row * NH + c;
    h0f[idx] = s;
    hf[idx] = s;
  }
}

// ---------------- va1 = gat_W @ a1, va2 = gat_W @ a2 ----------------
__global__ __launch_bounds__(256)
void wv_kernel(const float* __restrict__ W, const float* __restrict__ a,
               float* __restrict__ va1, float* __restrict__ va2) {
  int k = blockIdx.x, tid = threadIdx.x;
  float s1 = 0.f, s2 = 0.f;
  for (int n = tid; n < NH; n += 256) {
    float w = W[(long)k * NH + n];
    s1 += w * a[n];
    s2 += w * a[NH + n];
  }
#pragma unroll
  for (int o = 32; o; o >>= 1) { s1 += __shfl_down(s1, o); s2 += __shfl_down(s2, o); }
  __shared__ float r1[4], r2[4];
  int wave = tid >> 6;
  if ((tid & 63) == 0) { r1[wave] = s1; r2[wave] = s2; }
  __syncthreads();
  if (tid == 0) {
    va1[k] = r1[0] + r1[1] + r1[2] + r1[3];
    va2[k] = r2[0] + r2[1] + r2[2] + r2[3];
  }
}

// ---------------- f = h @ va1, g = h @ va2 ----------------
__global__ __launch_bounds__(256)
void fg_kernel(const float* __restrict__ h, const float* __restrict__ va1,
               const float* __restrict__ va2, float* __restrict__ fv,
               float* __restrict__ gv) {
  int row = blockIdx.x, tid = threadIdx.x;
  float s1 = 0.f, s2 = 0.f;
  for (int k = tid; k < NH; k += 256) {
    float v = h[(long)row * NH + k];
    s1 += v * va1[k];
    s2 += v * va2[k];
  }
#pragma unroll
  for (int o = 32; o; o >>= 1) { s1 += __shfl_down(s1, o); s2 += __shfl_down(s2, o); }
  __shared__ float r1[4], r2[4];
  int wave = tid >> 6;
  if ((tid & 63) == 0) { r1[wave] = s1; r2[wave] = s2; }
  __syncthreads();
  if (tid == 0) {
    fv[row] = r1[0] + r1[1] + r1[2] + r1[3];
    gv[row] = r2[0] + r2[1] + r2[2] + r2[3];
  }
}

// ---------------- attention pass 1: per-row max & denom ----------------
__global__ __launch_bounds__(256)
void attn_ml(const int* __restrict__ adj, const float* __restrict__ f,
             const float* __restrict__ g, float* __restrict__ Mr,
             float* __restrict__ Lr) {
  const int row = blockIdx.x, tid = threadIdx.x;
  const float fi = f[row];
  const int4* arow = (const int4*)(adj + (long)row * NN);
  float m = -3.0e38f, s = 0.f;
  for (int c = tid; c < NN / 4; c += 256) {
    int4 a = arow[c];
    float4 gg = *(const float4*)(g + c * 4);
#pragma unroll
    for (int t = 0; t < 4; ++t) {
      int av = (t == 0) ? a.x : (t == 1) ? a.y : (t == 2) ? a.z : a.w;
      float gvv = (t == 0) ? gg.x : (t == 1) ? gg.y : (t == 2) ? gg.z : gg.w;
      if (av > 0) {
        float e = fi + gvv;
        e = e > 0.f ? e : 0.2f * e;
        if (e > m) { s = s * __expf(m - e) + 1.f; m = e; }
        else s += __expf(e - m);
      }
    }
  }
#pragma unroll
  for (int o = 32; o; o >>= 1) {
    float m2 = __shfl_down(m, o), s2 = __shfl_down(s, o);
    float mn = fmaxf(m, m2);
    s = s * __expf(m - mn) + s2 * __expf(m2 - mn);
    m = mn;
  }
  __shared__ float ms[4], ss[4];
  int wave = tid >> 6;
  if ((tid & 63) == 0) { ms[wave] = m; ss[wave] = s; }
  __syncthreads();
  if (tid == 0) {
    float mm = ms[0], sv = ss[0];
    for (int w = 1; w < 4; ++w) {
      float mn = fmaxf(mm, ms[w]);
      sv = sv * __expf(mm - mn) + ss[w] * __expf(ms[w] - mn);
      mm = mn;
    }
    Mr[row] = mm;
    Lr[row] = sv;
  }
}

// ---------------- attention pass 2: P (bf16) ----------------
__global__ __launch_bounds__(256)
void attn_p(const int* __restrict__ adj, const float* __restrict__ f,
            const float* __restrict__ g, const float* __restrict__ Mr,
            const float* __restrict__ Lr, us* __restrict__ P) {
  long gid = blockIdx.x * 256L + threadIdx.x;
  int row = (int)(gid >> 11);
  int jc = (int)(gid & 2047) * 4;
  float fi = f[row], m = Mr[row], l = Lr[row];
  bool uni = !(l > 0.f);
  float inv = uni ? 0.f : 1.f / l;
  int4 a = *(const int4*)(adj + ((long)row << 13) + jc);
  float4 gg = *(const float4*)(g + jc);
  float p[4];
#pragma unroll
  for (int t = 0; t < 4; ++t) {
    int av = (t == 0) ? a.x : (t == 1) ? a.y : (t == 2) ? a.z : a.w;
    float gvv = (t == 0) ? gg.x : (t == 1) ? gg.y : (t == 2) ? gg.z : gg.w;
    float e = fi + gvv;
    e = e > 0.f ? e : 0.2f * e;
    float pv = (av > 0) ? __expf(e - m) * inv : 0.f;
    if (uni) pv = 1.f / (float)NN;
    p[t] = pv;
  }
  *(ushort4*)(P + ((long)row << 13) + jc) =
      make_ushort4(f2bf(p[0]), f2bf(p[1]), f2bf(p[2]), f2bf(p[3]));
}

extern "C" void kernel_launch(void* const* d_in, const int* in_sizes, int n_in,
                              void* d_out, int out_size, void* d_ws, size_t ws_size,
                              hipStream_t stream) {
  const float* x      = (const float*)d_in[0];
  const float* dist   = (const float*)d_in[1];
  const int*   adj    = (const int*)d_in[2];
  const float* fc_W   = (const float*)d_in[3];
  const float* fc_b   = (const float*)d_in[4];
  const float* conv_W = (const float*)d_in[5];
  const float* gat_W  = (const float*)d_in[6];
  const float* gat_a  = (const float*)d_in[7];
  const float* cls1_W = (const float*)d_in[8];
  const float* cls1_b = (const float*)d_in[9];
  const float* cls3_W = (const float*)d_in[10];
  const float* cls3_b = (const float*)d_in[11];
  float* out = (float*)d_out;

  char* p = (char*)d_ws;
  auto alloc = [&](size_t bytes) {
    char* r = p;
    p += (bytes + 255) & ~(size_t)255;
    return r;
  };
  us* distb   = (us*)alloc((size_t)NN * NN * 2);
  float* h0f  = (float*)alloc((size_t)NN * NH * 4);
  float* hf   = (float*)alloc((size_t)NN * NH * 4);
  float* supf = (float*)alloc((size_t)NN * NH * 4);
  us* supb    = (us*)alloc((size_t)NN * NH * 2);
  us* hb      = (us*)alloc((size_t)NN * NH * 2);
  us* hTb     = (us*)alloc((size_t)NN * NH * 2);
  us* convWT  = (us*)alloc((size_t)7 * NH * NH * 2);
  us* gatWT   = (us*)alloc((size_t)NH * NH * 2);
  us* W1t     = (us*)alloc((size_t)64 * NH * 2);
  float* va1 = (float*)alloc(NH * 4);
  float* va2 = (float*)alloc(NH * 4);
  float* fv  = (float*)alloc(NN * 4);
  float* gv  = (float*)alloc(NN * 4);
  float* Mr  = (float*)alloc(NN * 4);
  float* Lr  = (float*)alloc(NN * 4);

  float th[7];
  for (int l = 0; l < 7; ++l) {
    float t = logf(1.5f / (float)(l + 1) + 1.f);
    th[l] = t < 1.f ? t : 1.f;
  }
  float th9 = logf(1.5f / 9.f + 1.f);

  f32_to_bf16_vec<<<(NN * (long)NN) / (4 * 256), 256, 0, stream>>>(dist, distb);
  for (int i = 0; i < 7; ++i)
    transpose_f32_bf16<<<dim3(32, 32), 256, 0, stream>>>(
        conv_W + (size_t)i * NH * NH, convWT + (size_t)i * NH * NH, NH, NH);
  transpose_f32_bf16<<<dim3(32, 32), 256, 0, stream>>>(gat_W, gatWT, NH, NH);
  transpose_f32_bf16<<<dim3(2, 32), 256, 0, stream>>>(cls1_W, W1t, NH, 64);

  fc_kernel<<<NN, 256, 0, stream>>>(x, fc_W, fc_b, h0f, hf);
  transpose_f32_bf16<<<dim3(NH / 32, NN / 32), 256, 0, stream>>>(hf, hTb, NN, NH);

  for (int l = 0; l < 7; ++l) {
    gemm_big<<<256, 256, 0, stream>>>(distb, hTb, h0f, supf, supb);
    gemm_db<1><<<512, 256, 0, stream>>>(supb, convWT + (size_t)l * NH * NH, NH,
                                        supf, hf, nullptr, hTb, th[l]);
  }

  wv_kernel<<<NH, 256, 0, stream>>>(gat_W, gat_a, va1, va2);
  fg_kernel<<<NN, 256, 0, stream>>>(hf, va1, va2, fv, gv);
  attn_ml<<<NN, 256, 0, stream>>>(adj, fv, gv, Mr, Lr);
  attn_p<<<(NN * (long)NN) / (4 * 256), 256, 0, stream>>>(adj, fv, gv, Mr, Lr, distb);

  gemm_big<<<256, 256, 0, stream>>>(distb, hTb, h0f, supf, supb);
  gemm_db<2><<<512, 256, 0, stream>>>(supb, gatWT, NH, supf, hf, hb, nullptr, th9);

  cls_gemm<<<64, 256, 0, stream>>>(hb, W1t, cls1_b, cls3_W, cls3_b, out);
}